// Round 1
// baseline (57.355 us; speedup 1.0000x reference)
//
#include <hip/hip_runtime.h>

// OurButterflyLayer: N=4096, LOGN=12, IN=1024, OUT=4096, BATCH=8192
//
// out[s,j] = sum_{c<1024} input[s,c] * B[or[j],c]  where B = M11*...*M0,
// M_i = diag(a_i) + P_i diag(b_i), P_i = xor-perm by (1<<i).
// Equivalent: y = M11...M0 * pad(input_row); out[s,j] = y[or[j]].
// Elements >=1024 stay zero through stages 0..9 (strides < 1024 never mix
// them in), and stages 10,11 reduce to out_vec[r] = m[r]*z[r&1023] with
//   m[r] = (r&2048 ? B11 : A11)[r&2047] * (r&1024 ? B10 : A10)[r&1023].
// So: z = 10-stage butterfly on the 1024-float row; out[s,j] = scale[j]*z[src[j]].

__device__ __forceinline__ int swz(int e) {
    // XOR lane-derived bits [6:5] into [3:2]: keeps float4 alignment,
    // spreads the 64-lane b128 z-write across 8 bank groups instead of 2.
    return e ^ (((e >> 5) & 3) << 2);
}

__global__ void __launch_bounds__(256) bfly_prep(
    const float* __restrict__ lp, const int* __restrict__ orow,
    float* __restrict__ scale, int* __restrict__ src)
{
    int j = blockIdx.x * 256 + threadIdx.x;
    if (j >= 4096) return;
    int r = orow[j];
    int c = r & 1023;
    int u = r & 2047;
    const float* A10 = lp + 20 * 4096;
    const float* B10 = lp + 21 * 4096;
    const float* A11 = lp + 22 * 4096;
    const float* B11 = lp + 23 * 4096;
    float f11 = (r & 2048) ? B11[u] : A11[u];
    float f10 = (r & 1024) ? B10[c] : A10[c];
    scale[j] = f11 * f10;
    src[j] = c;
}

__global__ void __launch_bounds__(256) bfly_main(
    const float* __restrict__ inp, const float* __restrict__ lp,
    const float* __restrict__ scale, const int* __restrict__ src,
    float* __restrict__ out)
{
    const int wave = threadIdx.x >> 6;
    const int lane = threadIdx.x & 63;
    const int s0 = (blockIdx.x * 4 + wave) * 2;   // 2 samples per wave

    __shared__ float zbuf[4][1024];               // wave-private z regions
    float* zw = zbuf[wave];

    float x0[16], x1[16];
    {
        const float4* p0 = reinterpret_cast<const float4*>(inp + (size_t)s0 * 1024 + lane * 16);
        const float4* p1 = reinterpret_cast<const float4*>(inp + (size_t)(s0 + 1) * 1024 + lane * 16);
        #pragma unroll
        for (int c = 0; c < 4; ++c) {
            float4 v0 = p0[c]; float4 v1 = p1[c];
            x0[4*c+0] = v0.x; x0[4*c+1] = v0.y; x0[4*c+2] = v0.z; x0[4*c+3] = v0.w;
            x1[4*c+0] = v1.x; x1[4*c+1] = v1.y; x1[4*c+2] = v1.z; x1[4*c+3] = v1.w;
        }
    }

    // stages 0..3: pairs live inside the lane's 16 registers (static k^s)
    #pragma unroll
    for (int i = 0; i < 4; ++i) {
        float a[16], b[16];
        const float4* A = reinterpret_cast<const float4*>(lp + (size_t)(2*i)   * 4096 + lane * 16);
        const float4* B = reinterpret_cast<const float4*>(lp + (size_t)(2*i+1) * 4096 + lane * 16);
        #pragma unroll
        for (int c = 0; c < 4; ++c) {
            float4 va = A[c], vb = B[c];
            a[4*c+0]=va.x; a[4*c+1]=va.y; a[4*c+2]=va.z; a[4*c+3]=va.w;
            b[4*c+0]=vb.x; b[4*c+1]=vb.y; b[4*c+2]=vb.z; b[4*c+3]=vb.w;
        }
        const int s = 1 << i;
        float y0[16], y1[16];
        #pragma unroll
        for (int k = 0; k < 16; ++k) {
            y0[k] = a[k] * x0[k] + b[k ^ s] * x0[k ^ s];
            y1[k] = a[k] * x1[k] + b[k ^ s] * x1[k ^ s];
        }
        #pragma unroll
        for (int k = 0; k < 16; ++k) { x0[k] = y0[k]; x1[k] = y1[k]; }
    }

    // stages 4..9: partner lives in lane^d; value via shfl_xor, coeff loaded
    // from the partner's contiguous 16-element block.
    #pragma unroll
    for (int i = 4; i < 10; ++i) {
        const int d = 1 << (i - 4);
        float a[16], b[16];
        const float4* A = reinterpret_cast<const float4*>(lp + (size_t)(2*i)   * 4096 + lane * 16);
        const float4* B = reinterpret_cast<const float4*>(lp + (size_t)(2*i+1) * 4096 + (lane ^ d) * 16);
        #pragma unroll
        for (int c = 0; c < 4; ++c) {
            float4 va = A[c], vb = B[c];
            a[4*c+0]=va.x; a[4*c+1]=va.y; a[4*c+2]=va.z; a[4*c+3]=va.w;
            b[4*c+0]=vb.x; b[4*c+1]=vb.y; b[4*c+2]=vb.z; b[4*c+3]=vb.w;
        }
        #pragma unroll
        for (int k = 0; k < 16; ++k) {
            float xp0 = __shfl_xor(x0[k], d, 64);
            float xp1 = __shfl_xor(x1[k], d, 64);
            x0[k] = a[k] * x0[k] + b[k] * xp0;
            x1[k] = a[k] * x1[k] + b[k] * xp1;
        }
    }

    // epilogue per sample: z -> swizzled LDS, then coalesced scaled gather
    auto emit = [&](const float* xr, int s) {
        #pragma unroll
        for (int c = 0; c < 4; ++c) {
            int e = lane * 16 + 4 * c;
            float4 v = make_float4(xr[4*c+0], xr[4*c+1], xr[4*c+2], xr[4*c+3]);
            *reinterpret_cast<float4*>(&zw[swz(e)]) = v;
        }
        // region is wave-private: no barrier needed, compiler orders ds ops
        const int4*   srv = reinterpret_cast<const int4*>(src);
        const float4* scv = reinterpret_cast<const float4*>(scale);
        float4* outp = reinterpret_cast<float4*>(out + (size_t)s * 4096);
        #pragma unroll
        for (int it = 0; it < 16; ++it) {
            int j4 = it * 64 + lane;
            int4   si = srv[j4];
            float4 sc = scv[j4];
            float4 r;
            r.x = sc.x * zw[swz(si.x)];
            r.y = sc.y * zw[swz(si.y)];
            r.z = sc.z * zw[swz(si.z)];
            r.w = sc.w * zw[swz(si.w)];
            outp[j4] = r;
        }
    };
    emit(x0, s0);
    emit(x1, s0 + 1);
}

extern "C" void kernel_launch(void* const* d_in, const int* in_sizes, int n_in,
                              void* d_out, int out_size, void* d_ws, size_t ws_size,
                              hipStream_t stream) {
    const float* inp  = (const float*)d_in[0];   // (8192, 1024) f32
    const float* lp   = (const float*)d_in[1];   // (24, 4096)  f32
    const int*   orow = (const int*)d_in[2];     // (4096,)     i32
    float* out = (float*)d_out;                  // (8192, 4096) f32

    float* scale = (float*)d_ws;                       // 4096 f32
    int*   src   = (int*)((char*)d_ws + 4096 * 4);     // 4096 i32  (32 KiB total)

    bfly_prep<<<16, 256, 0, stream>>>(lp, orow, scale, src);
    bfly_main<<<1024, 256, 0, stream>>>(inp, lp, scale, src, out);
}

// Round 2
// 50.140 us; speedup vs baseline: 1.1439x; 1.1439x over previous
//
#include <hip/hip_runtime.h>

// OurButterflyLayer: N=4096, LOGN=12, IN=1024, OUT=4096, BATCH=8192
//
// out[s,j] = sum_{c<1024} input[s,c] * B[or[j],c],  B = M11*...*M0,
// M_i = diag(a_i) + P_i diag(b_i), P_i = xor-perm by (1<<i).
// Elements >=1024 stay zero through stages 0..9 (strides < 1024), and stages
// 10,11 reduce to a per-output scale:  out[s,j] = scale[j] * z[src[j]], where
// z = 10-stage butterfly applied to the 1024-float input row.
//
// Round-2 structure: 256-thread blocks (4 waves), 4 samples/wave.
// Stage 4..9 coefficients staged once per block into XOR-swizzled LDS (48 KB),
// region reused as the per-wave z scratch for the epilogue gather.

typedef float f4 __attribute__((ext_vector_type(4)));
typedef int   i4 __attribute__((ext_vector_type(4)));

__device__ __forceinline__ int swz(int e) {
    // XOR float-index bits [6:5] into [3:2]: keeps float4 alignment; makes
    // both the 64B-stride coeff reads and the z writes bank-conflict-free.
    return e ^ (((e >> 5) & 3) << 2);
}

__global__ void __launch_bounds__(256) bfly_prep(
    const float* __restrict__ lp, const int* __restrict__ orow,
    float* __restrict__ scale, int* __restrict__ src)
{
    int j = blockIdx.x * 256 + threadIdx.x;
    if (j >= 4096) return;
    int r = orow[j];
    int c = r & 1023;
    int u = r & 2047;
    const float* A10 = lp + 20 * 4096;
    const float* B10 = lp + 21 * 4096;
    const float* A11 = lp + 22 * 4096;
    const float* B11 = lp + 23 * 4096;
    float f11 = (r & 2048) ? B11[u] : A11[u];
    float f10 = (r & 1024) ? B10[c] : A10[c];
    scale[j] = f11 * f10;
    src[j] = c;
}

__global__ void __launch_bounds__(256, 2) bfly_main(
    const float* __restrict__ inp, const float* __restrict__ lp,
    const float* __restrict__ scale, const int* __restrict__ src,
    float* __restrict__ out)
{
    // 12 rows x 1024 floats: a,b for stages 4..9 (swizzled). Reused as zbuf.
    __shared__ __align__(16) float cf[12 * 1024];
    const int t = threadIdx.x;
    const int wave = t >> 6, lane = t & 63;

    // cooperative coeff staging: lp rows 8..19, first 1024 floats of each
    #pragma unroll
    for (int q = 0; q < 12; ++q) {
        const f4 v = *reinterpret_cast<const f4*>(lp + (size_t)(8 + q) * 4096 + t * 4);
        *reinterpret_cast<f4*>(&cf[q * 1024 + swz(t * 4)]) = v;
    }

    const int sBase = blockIdx.x * 16 + wave * 4;
    float x[4][16];
    #pragma unroll
    for (int m = 0; m < 4; ++m) {
        const f4* p = reinterpret_cast<const f4*>(inp + (size_t)(sBase + m) * 1024 + lane * 16);
        #pragma unroll
        for (int c = 0; c < 4; ++c) {
            f4 v = __builtin_nontemporal_load(p + c);
            x[m][4*c+0] = v.x; x[m][4*c+1] = v.y; x[m][4*c+2] = v.z; x[m][4*c+3] = v.w;
        }
    }

    __syncthreads();   // cf ready (input loads overlapped with staging)

    // stages 0..3: coeff from global (L1-hot, 8 KB/stage/wave), pairs in-lane
    #pragma unroll
    for (int i = 0; i < 4; ++i) {
        float a[16], b[16];
        const f4* A = reinterpret_cast<const f4*>(lp + (size_t)(2*i)   * 4096 + lane * 16);
        const f4* B = reinterpret_cast<const f4*>(lp + (size_t)(2*i+1) * 4096 + lane * 16);
        #pragma unroll
        for (int c = 0; c < 4; ++c) {
            f4 va = A[c], vb = B[c];
            a[4*c+0]=va.x; a[4*c+1]=va.y; a[4*c+2]=va.z; a[4*c+3]=va.w;
            b[4*c+0]=vb.x; b[4*c+1]=vb.y; b[4*c+2]=vb.z; b[4*c+3]=vb.w;
        }
        const int s = 1 << i;
        #pragma unroll
        for (int m = 0; m < 4; ++m) {
            #pragma unroll
            for (int k = 0; k < 16; ++k) {
                if (!(k & s)) {
                    float lo = x[m][k], hi = x[m][k | s];
                    x[m][k]     = a[k]     * lo + b[k | s] * hi;
                    x[m][k | s] = a[k | s] * hi + b[k]     * lo;
                }
            }
        }
    }

    // stages 4..9: coeff from swizzled LDS, partner value via shfl_xor
    #pragma unroll
    for (int i = 4; i < 10; ++i) {
        const int d = 1 << (i - 4);
        float a[16], b[16];
        const float* arow = &cf[(size_t)(i - 4) * 2048];
        const float* brow = arow + 1024;
        #pragma unroll
        for (int c = 0; c < 4; ++c) {
            f4 va = *reinterpret_cast<const f4*>(&arow[swz(lane * 16 + 4 * c)]);
            f4 vb = *reinterpret_cast<const f4*>(&brow[swz((lane ^ d) * 16 + 4 * c)]);
            a[4*c+0]=va.x; a[4*c+1]=va.y; a[4*c+2]=va.z; a[4*c+3]=va.w;
            b[4*c+0]=vb.x; b[4*c+1]=vb.y; b[4*c+2]=vb.z; b[4*c+3]=vb.w;
        }
        #pragma unroll
        for (int m = 0; m < 4; ++m) {
            #pragma unroll
            for (int k = 0; k < 16; ++k) {
                float xp = __shfl_xor(x[m][k], d, 64);
                x[m][k] = a[k] * x[m][k] + b[k] * xp;
            }
        }
    }

    __syncthreads();   // all coeff reads done; reuse cf as z scratch

    float* zw = &cf[(size_t)wave * 2048];       // 2 samples per pass
    const i4* srv = reinterpret_cast<const i4*>(src);
    const f4* scv = reinterpret_cast<const f4*>(scale);

    #pragma unroll
    for (int p = 0; p < 2; ++p) {
        #pragma unroll
        for (int h = 0; h < 2; ++h) {
            const float* xr = x[p * 2 + h];
            #pragma unroll
            for (int c = 0; c < 4; ++c) {
                int e = lane * 16 + 4 * c;
                f4 v = { xr[4*c+0], xr[4*c+1], xr[4*c+2], xr[4*c+3] };
                *reinterpret_cast<f4*>(&zw[h * 1024 + swz(e)]) = v;
            }
        }
        // wave-private region: in-wave lgkmcnt ordering suffices, no barrier
        #pragma unroll 4
        for (int it = 0; it < 16; ++it) {
            int j4 = it * 64 + lane;
            i4 si = srv[j4];
            f4 sc = scv[j4];
            #pragma unroll
            for (int h = 0; h < 2; ++h) {
                const float* zh = &zw[h * 1024];
                f4 r;
                r.x = sc.x * zh[swz(si.x)];
                r.y = sc.y * zh[swz(si.y)];
                r.z = sc.z * zh[swz(si.z)];
                r.w = sc.w * zh[swz(si.w)];
                __builtin_nontemporal_store(
                    r, reinterpret_cast<f4*>(out + (size_t)(sBase + p * 2 + h) * 4096) + j4);
            }
        }
    }
}

extern "C" void kernel_launch(void* const* d_in, const int* in_sizes, int n_in,
                              void* d_out, int out_size, void* d_ws, size_t ws_size,
                              hipStream_t stream) {
    const float* inp  = (const float*)d_in[0];   // (8192, 1024) f32
    const float* lp   = (const float*)d_in[1];   // (24, 4096)  f32
    const int*   orow = (const int*)d_in[2];     // (4096,)     i32
    float* out = (float*)d_out;                  // (8192, 4096) f32

    float* scale = (float*)d_ws;                       // 4096 f32
    int*   src   = (int*)((char*)d_ws + 4096 * 4);     // 4096 i32

    bfly_prep<<<16, 256, 0, stream>>>(lp, orow, scale, src);
    bfly_main<<<512, 256, 0, stream>>>(inp, lp, scale, src, out);
}